// Round 1
// baseline (2393.048 us; speedup 1.0000x reference)
//
#include <hip/hip_runtime.h>

#define H 768
#define NH 12
#define HD 64
#define BSZ 16
#define SEQ 1024
#define MTOK (BSZ * SEQ)   // 16384

// ---------------------------------------------------------------------------
// Generic tiled GEMM: C[M,N] = A[M,K] @ B[K,N] + bias[N]   (fp32)
// 64x64 tile, BK=16, 256 threads, 4x4 outputs/thread.
// LDS rows padded to 68 floats (272 B, 16B-aligned) to spread banks.
// ---------------------------------------------------------------------------
__global__ __launch_bounds__(256) void gemm_bias_kernel(
    const float* __restrict__ A, const float* __restrict__ Bm,
    const float* __restrict__ bias, float* __restrict__ C,
    int M, int N, int K)
{
    __shared__ float As[16][68];   // [k][m] (transposed on store)
    __shared__ float Bs[16][68];   // [k][n]

    const int tid = threadIdx.x;
    const int tx = tid & 15, ty = tid >> 4;
    const int rowBase = blockIdx.y * 64;
    const int colBase = blockIdx.x * 64;

    const int arow = tid >> 2, acol4 = tid & 3;    // A loader: 64x16, 1 float4/thread
    const int brow = tid >> 4, bcol4 = tid & 15;   // B loader: 16x64, 1 float4/thread

    float acc[4][4] = {};

    for (int k0 = 0; k0 < K; k0 += 16) {
        float4 av = *reinterpret_cast<const float4*>(
            &A[(size_t)(rowBase + arow) * K + k0 + acol4 * 4]);
        float4 bv = *reinterpret_cast<const float4*>(
            &Bm[(size_t)(k0 + brow) * N + colBase + bcol4 * 4]);
        As[acol4 * 4 + 0][arow] = av.x;
        As[acol4 * 4 + 1][arow] = av.y;
        As[acol4 * 4 + 2][arow] = av.z;
        As[acol4 * 4 + 3][arow] = av.w;
        *reinterpret_cast<float4*>(&Bs[brow][bcol4 * 4]) = bv;
        __syncthreads();

        #pragma unroll
        for (int kk = 0; kk < 16; ++kk) {
            float4 a4 = *reinterpret_cast<const float4*>(&As[kk][ty * 4]);
            float4 b4 = *reinterpret_cast<const float4*>(&Bs[kk][tx * 4]);
            acc[0][0] += a4.x * b4.x; acc[0][1] += a4.x * b4.y;
            acc[0][2] += a4.x * b4.z; acc[0][3] += a4.x * b4.w;
            acc[1][0] += a4.y * b4.x; acc[1][1] += a4.y * b4.y;
            acc[1][2] += a4.y * b4.z; acc[1][3] += a4.y * b4.w;
            acc[2][0] += a4.z * b4.x; acc[2][1] += a4.z * b4.y;
            acc[2][2] += a4.z * b4.z; acc[2][3] += a4.z * b4.w;
            acc[3][0] += a4.w * b4.x; acc[3][1] += a4.w * b4.y;
            acc[3][2] += a4.w * b4.z; acc[3][3] += a4.w * b4.w;
        }
        __syncthreads();
    }

    const int c0 = colBase + tx * 4;
    float4 bb = *reinterpret_cast<const float4*>(&bias[c0]);
    #pragma unroll
    for (int i = 0; i < 4; ++i) {
        int r = rowBase + ty * 4 + i;
        float4 o;
        o.x = acc[i][0] + bb.x; o.y = acc[i][1] + bb.y;
        o.z = acc[i][2] + bb.z; o.w = acc[i][3] + bb.w;
        *reinterpret_cast<float4*>(&C[(size_t)r * N + c0]) = o;
    }
}

// ---------------------------------------------------------------------------
// Flash-style causal attention.
// qkv: [B*S, 3H] rows = [q(768) | k(768) | v(768)], head h occupies cols h*64..
// out: [B*S, H]
// Block: 256 threads handles one (b, h, 64-row q-tile). Online softmax.
// ---------------------------------------------------------------------------
__global__ __launch_bounds__(256) void attn_kernel(
    const float* __restrict__ qkv, float* __restrict__ out)
{
    __shared__ float Qs[64][68];
    __shared__ float Ks[64][68];
    __shared__ float Vs[64][68];
    __shared__ float Ps[64][68];

    const int tid = threadIdx.x;
    const int tx = tid & 15, ty = tid >> 4;
    const int qt = blockIdx.x;   // q tile 0..15
    const int h  = blockIdx.y;   // head 0..11
    const int b  = blockIdx.z;   // batch 0..15

    const int lrow = tid >> 4;   // 0..15 (loader row stagger)
    const int lc4  = tid & 15;   // 0..15 -> col = lc4*4

    // load Q tile (pre-scaled by 1/sqrt(64) = 0.125)
    #pragma unroll
    for (int r = 0; r < 4; ++r) {
        int row = lrow + r * 16;
        size_t g = ((size_t)(b * SEQ + qt * 64 + row)) * (3 * H) + h * HD + lc4 * 4;
        float4 v = *reinterpret_cast<const float4*>(&qkv[g]);
        v.x *= 0.125f; v.y *= 0.125f; v.z *= 0.125f; v.w *= 0.125f;
        *reinterpret_cast<float4*>(&Qs[row][lc4 * 4]) = v;
    }

    float o[4][4] = {};
    float mrun[4] = {-1e30f, -1e30f, -1e30f, -1e30f};
    float lrun[4] = {};

    for (int kt = 0; kt <= qt; ++kt) {
        __syncthreads();   // prior iteration's Ks/Vs/Ps readers done
        #pragma unroll
        for (int r = 0; r < 4; ++r) {
            int row = lrow + r * 16;
            size_t g = ((size_t)(b * SEQ + kt * 64 + row)) * (3 * H) + H + h * HD + lc4 * 4;
            *reinterpret_cast<float4*>(&Ks[row][lc4 * 4]) =
                *reinterpret_cast<const float4*>(&qkv[g]);
            *reinterpret_cast<float4*>(&Vs[row][lc4 * 4]) =
                *reinterpret_cast<const float4*>(&qkv[g + H]);
        }
        __syncthreads();

        // S tile: rows qr = ty*4+i, cols kc = j*16+tx
        float sv[4][4] = {};
        #pragma unroll
        for (int d4 = 0; d4 < 16; ++d4) {
            float4 q4[4], k4[4];
            #pragma unroll
            for (int i = 0; i < 4; ++i)
                q4[i] = *reinterpret_cast<const float4*>(&Qs[ty * 4 + i][d4 * 4]);
            #pragma unroll
            for (int j = 0; j < 4; ++j)
                k4[j] = *reinterpret_cast<const float4*>(&Ks[j * 16 + tx][d4 * 4]);
            #pragma unroll
            for (int i = 0; i < 4; ++i)
                #pragma unroll
                for (int j = 0; j < 4; ++j) {
                    sv[i][j] += q4[i].x * k4[j].x + q4[i].y * k4[j].y
                              + q4[i].z * k4[j].z + q4[i].w * k4[j].w;
                }
        }

        if (kt == qt) {   // causal mask within diagonal tile
            #pragma unroll
            for (int i = 0; i < 4; ++i)
                #pragma unroll
                for (int j = 0; j < 4; ++j)
                    if (j * 16 + tx > ty * 4 + i) sv[i][j] = -3e38f;
        }

        // online softmax update (per row i; row group = 16 lanes same ty)
        #pragma unroll
        for (int i = 0; i < 4; ++i) {
            float mx = fmaxf(fmaxf(sv[i][0], sv[i][1]), fmaxf(sv[i][2], sv[i][3]));
            #pragma unroll
            for (int off = 1; off < 16; off <<= 1)
                mx = fmaxf(mx, __shfl_xor(mx, off, 64));
            float mnew = fmaxf(mrun[i], mx);
            float sc = __expf(mrun[i] - mnew);
            mrun[i] = mnew;
            float rs = 0.f;
            #pragma unroll
            for (int j = 0; j < 4; ++j) {
                float p = __expf(sv[i][j] - mnew);
                sv[i][j] = p;
                rs += p;
            }
            #pragma unroll
            for (int off = 1; off < 16; off <<= 1)
                rs += __shfl_xor(rs, off, 64);
            lrun[i] = lrun[i] * sc + rs;
            o[i][0] *= sc; o[i][1] *= sc; o[i][2] *= sc; o[i][3] *= sc;
        }

        // stage P to LDS
        #pragma unroll
        for (int i = 0; i < 4; ++i)
            #pragma unroll
            for (int j = 0; j < 4; ++j)
                Ps[ty * 4 + i][j * 16 + tx] = sv[i][j];
        __syncthreads();

        // O += P @ V : rows qr = ty*4+i, cols oc = tx*4+j2
        #pragma unroll
        for (int kc4 = 0; kc4 < 16; ++kc4) {
            float4 p4[4];
            #pragma unroll
            for (int i = 0; i < 4; ++i)
                p4[i] = *reinterpret_cast<const float4*>(&Ps[ty * 4 + i][kc4 * 4]);
            #pragma unroll
            for (int m = 0; m < 4; ++m) {
                float4 v4 = *reinterpret_cast<const float4*>(&Vs[kc4 * 4 + m][tx * 4]);
                float pm0 = p4[0].x, pm1 = p4[1].x, pm2 = p4[2].x, pm3 = p4[3].x;
                float pv[4];
                pv[0] = (m == 0) ? p4[0].x : (m == 1) ? p4[0].y : (m == 2) ? p4[0].z : p4[0].w;
                pv[1] = (m == 0) ? p4[1].x : (m == 1) ? p4[1].y : (m == 2) ? p4[1].z : p4[1].w;
                pv[2] = (m == 0) ? p4[2].x : (m == 1) ? p4[2].y : (m == 2) ? p4[2].z : p4[2].w;
                pv[3] = (m == 0) ? p4[3].x : (m == 1) ? p4[3].y : (m == 2) ? p4[3].z : p4[3].w;
                (void)pm0; (void)pm1; (void)pm2; (void)pm3;
                #pragma unroll
                for (int i = 0; i < 4; ++i) {
                    o[i][0] += pv[i] * v4.x;
                    o[i][1] += pv[i] * v4.y;
                    o[i][2] += pv[i] * v4.z;
                    o[i][3] += pv[i] * v4.w;
                }
            }
        }
    }

    // epilogue: normalize and write [B*S, H]
    #pragma unroll
    for (int i = 0; i < 4; ++i) {
        float inv = 1.0f / lrun[i];
        float4 ov;
        ov.x = o[i][0] * inv; ov.y = o[i][1] * inv;
        ov.z = o[i][2] * inv; ov.w = o[i][3] * inv;
        size_t g = ((size_t)(b * SEQ + qt * 64 + ty * 4 + i)) * H + h * HD + tx * 4;
        *reinterpret_cast<float4*>(&out[g]) = ov;
    }
}

// ---------------------------------------------------------------------------
extern "C" void kernel_launch(void* const* d_in, const int* in_sizes, int n_in,
                              void* d_out, int out_size, void* d_ws, size_t ws_size,
                              hipStream_t stream) {
    const float* x      = (const float*)d_in[0];
    const float* W_qkv  = (const float*)d_in[1];
    const float* b_qkv  = (const float*)d_in[2];
    const float* W_proj = (const float*)d_in[3];
    const float* b_proj = (const float*)d_in[4];
    float* outp = (float*)d_out;

    float* qkv     = (float*)d_ws;                          // [16384, 2304]
    float* attnout = qkv + (size_t)MTOK * (3 * H);          // [16384, 768]

    // 1) QKV projection: [16384,768] @ [768,2304] + b
    gemm_bias_kernel<<<dim3((3 * H) / 64, MTOK / 64), 256, 0, stream>>>(
        x, W_qkv, b_qkv, qkv, MTOK, 3 * H, H);

    // 2) causal flash attention per (q-tile, head, batch)
    attn_kernel<<<dim3(SEQ / 64, NH, BSZ), 256, 0, stream>>>(qkv, attnout);

    // 3) output projection: [16384,768] @ [768,768] + b
    gemm_bias_kernel<<<dim3(H / 64, MTOK / 64), 256, 0, stream>>>(
        attnout, W_proj, b_proj, outp, MTOK, H, H);
}

// Round 2
// 397.054 us; speedup vs baseline: 6.0270x; 6.0270x over previous
//
#include <hip/hip_runtime.h>

#define H 768
#define NH 12
#define HD 64
#define BSZ 16
#define SEQ 1024
#define MTOK (BSZ * SEQ)   // 16384
#define N3H (3 * H)        // 2304

typedef __attribute__((ext_vector_type(8))) short bf16x8;
typedef __attribute__((ext_vector_type(4))) float f32x4;
typedef __attribute__((ext_vector_type(8))) unsigned short us8;

__device__ __forceinline__ unsigned short f2bf(float f) {
    union { float f; unsigned u; } v; v.f = f;
    unsigned r = v.u + 0x7fffu + ((v.u >> 16) & 1u);   // RNE
    return (unsigned short)(r >> 16);
}

// ---------------------------------------------------------------------------
// fp32 -> bf16 elementwise convert (n multiple of 8)
// ---------------------------------------------------------------------------
__global__ __launch_bounds__(256) void cvt_bf16(
    const float* __restrict__ in, unsigned short* __restrict__ out, int n)
{
    int i = (blockIdx.x * 256 + threadIdx.x) * 8;
    if (i >= n) return;
    float4 a = *(const float4*)(in + i);
    float4 b = *(const float4*)(in + i + 4);
    us8 o;
    o[0]=f2bf(a.x); o[1]=f2bf(a.y); o[2]=f2bf(a.z); o[3]=f2bf(a.w);
    o[4]=f2bf(b.x); o[5]=f2bf(b.y); o[6]=f2bf(b.z); o[7]=f2bf(b.w);
    *(us8*)(out + i) = o;
}

// ---------------------------------------------------------------------------
// fp32 [Kd][Nd] -> bf16 transposed [Nd][Kd]  (64x64 LDS tiles)
// ---------------------------------------------------------------------------
__global__ __launch_bounds__(256) void tconv_bf16(
    const float* __restrict__ in, unsigned short* __restrict__ out, int Kd, int Nd)
{
    __shared__ float tile[64][65];
    int t = threadIdx.x;
    int n0 = blockIdx.x * 64, k0 = blockIdx.y * 64;
    #pragma unroll
    for (int r = 0; r < 4; ++r) {
        int kl = r * 16 + (t >> 4);
        float4 v = *(const float4*)(&in[(size_t)(k0 + kl) * Nd + n0 + (t & 15) * 4]);
        tile[kl][(t & 15) * 4 + 0] = v.x; tile[kl][(t & 15) * 4 + 1] = v.y;
        tile[kl][(t & 15) * 4 + 2] = v.z; tile[kl][(t & 15) * 4 + 3] = v.w;
    }
    __syncthreads();
    int nl = t >> 2, kc = (t & 3) * 16;
    us8 o0, o1;
    #pragma unroll
    for (int kk = 0; kk < 8; ++kk) o0[kk] = f2bf(tile[kc + kk][nl]);
    #pragma unroll
    for (int kk = 0; kk < 8; ++kk) o1[kk] = f2bf(tile[kc + 8 + kk][nl]);
    size_t ob = (size_t)(n0 + nl) * Kd + k0 + kc;
    *(us8*)(&out[ob]) = o0;
    *(us8*)(&out[ob + 8]) = o1;
}

// ---------------------------------------------------------------------------
// bf16 MFMA GEMM: C[M,N] = A[M,K] @ BT[N,K]^T + bias
// 128x128 tile, BK=64, 256 thr (4 waves, each 64x64). XOR-swizzled LDS.
// write_f32: 1 -> fp32 C, 0 -> bf16 C.
// ---------------------------------------------------------------------------
__global__ __launch_bounds__(256) void gemm_bf16(
    const unsigned short* __restrict__ A, const unsigned short* __restrict__ BT,
    const float* __restrict__ bias, void* __restrict__ Cout,
    int M, int N, int K, int write_f32)
{
    __shared__ char As[128 * 128];
    __shared__ char Bs[128 * 128];
    int t = threadIdx.x;
    int l = t & 63, w = t >> 6;
    int l16 = l & 15, l4 = l >> 4;
    int wm = w >> 1, wn = w & 1;
    int rowBase = blockIdx.y * 128, colBase = blockIdx.x * 128;

    f32x4 acc[4][4];
    #pragma unroll
    for (int i = 0; i < 4; ++i)
        #pragma unroll
        for (int j = 0; j < 4; ++j) acc[i][j] = (f32x4){0, 0, 0, 0};

    for (int k0 = 0; k0 < K; k0 += 64) {
        __syncthreads();
        #pragma unroll
        for (int i = 0; i < 4; ++i) {
            int lin = t + i * 256;
            int row = lin >> 3, seg = lin & 7;
            us8 av = *(const us8*)(&A[(size_t)(rowBase + row) * K + k0 + seg * 8]);
            *(us8*)(As + row * 128 + ((seg * 16) ^ ((row & 7) << 4))) = av;
            us8 bv = *(const us8*)(&BT[(size_t)(colBase + row) * K + k0 + seg * 8]);
            *(us8*)(Bs + row * 128 + ((seg * 16) ^ ((row & 7) << 4))) = bv;
        }
        __syncthreads();
        #pragma unroll
        for (int kh = 0; kh < 2; ++kh) {
            bf16x8 af[4], bfr[4];
            #pragma unroll
            for (int mi = 0; mi < 4; ++mi) {
                int row = wm * 64 + mi * 16 + l16;
                af[mi] = *(const bf16x8*)(As + row * 128 + ((l4 * 16 + kh * 64) ^ ((row & 7) << 4)));
            }
            #pragma unroll
            for (int ni = 0; ni < 4; ++ni) {
                int row = wn * 64 + ni * 16 + l16;
                bfr[ni] = *(const bf16x8*)(Bs + row * 128 + ((l4 * 16 + kh * 64) ^ ((row & 7) << 4)));
            }
            #pragma unroll
            for (int mi = 0; mi < 4; ++mi)
                #pragma unroll
                for (int ni = 0; ni < 4; ++ni)
                    acc[mi][ni] = __builtin_amdgcn_mfma_f32_16x16x32_bf16(
                        af[mi], bfr[ni], acc[mi][ni], 0, 0, 0);
        }
    }

    #pragma unroll
    for (int ni = 0; ni < 4; ++ni) {
        int col = colBase + wn * 64 + ni * 16 + l16;
        float bb = bias ? bias[col] : 0.f;
        #pragma unroll
        for (int mi = 0; mi < 4; ++mi) {
            #pragma unroll
            for (int j = 0; j < 4; ++j) {
                int row = rowBase + wm * 64 + mi * 16 + l4 * 4 + j;
                float v = acc[mi][ni][j] + bb;
                if (write_f32) ((float*)Cout)[(size_t)row * N + col] = v;
                else ((unsigned short*)Cout)[(size_t)row * N + col] = f2bf(v);
            }
        }
    }
}

// ---------------------------------------------------------------------------
// V transpose: qkv bf16 [MTOK][2304] (V part) -> vt bf16 [b][h][d=64][s=1024]
// ---------------------------------------------------------------------------
__global__ __launch_bounds__(256) void vtrans(
    const unsigned short* __restrict__ qkvb, unsigned short* __restrict__ vt)
{
    __shared__ char tile[64 * 128];
    int t = threadIdx.x;
    int st = blockIdx.x, h = blockIdx.y, b = blockIdx.z;
    int s0 = st * 64;
    {
        int s = t >> 2, dc = (t & 3) * 16;
        size_t g = (size_t)(b * SEQ + s0 + s) * N3H + 2 * H + h * HD + dc;
        us8 v0 = *(const us8*)(&qkvb[g]);
        us8 v1 = *(const us8*)(&qkvb[g + 8]);
        *(us8*)(tile + s * 128 + ((dc * 2) ^ ((s & 7) << 4))) = v0;
        *(us8*)(tile + s * 128 + ((dc * 2 + 16) ^ ((s & 7) << 4))) = v1;
    }
    __syncthreads();
    int d = t >> 2, sc = (t & 3) * 16;
    us8 o0, o1;
    #pragma unroll
    for (int kk = 0; kk < 8; ++kk) {
        int s = sc + kk;
        o0[kk] = *(const unsigned short*)(tile + s * 128 + ((d * 2) ^ ((s & 7) << 4)));
    }
    #pragma unroll
    for (int kk = 0; kk < 8; ++kk) {
        int s = sc + 8 + kk;
        o1[kk] = *(const unsigned short*)(tile + s * 128 + ((d * 2) ^ ((s & 7) << 4)));
    }
    size_t ob = ((size_t)((b * NH + h) * 64 + d)) * SEQ + s0 + sc;
    *(us8*)(&vt[ob]) = o0;
    *(us8*)(&vt[ob + 8]) = o1;
}

// ---------------------------------------------------------------------------
// Flash attention, bf16 MFMA. 4 waves/block; wave w owns q rows qt*64+w*16..+16.
// Q in regs; K and V^T staged per 64-key tile in swizzled LDS; online softmax.
// ---------------------------------------------------------------------------
__global__ __launch_bounds__(256) void attn_mfma(
    const unsigned short* __restrict__ qkvb,
    const unsigned short* __restrict__ vt,
    unsigned short* __restrict__ aout)
{
    __shared__ char Ks[64 * 128];
    __shared__ char Vs[64 * 128];
    __shared__ char Ps[4 * 16 * 128];
    int t = threadIdx.x;
    int l = t & 63, w = t >> 6;
    int qt = blockIdx.x, h = blockIdx.y, b = blockIdx.z;
    int l16 = l & 15, l4 = l >> 4;

    // Q fragments (A-operand): row = l16 of wave's 16 q rows, k = l4*8 (+32)
    bf16x8 qa0, qa1;
    {
        int qrow = qt * 64 + w * 16 + l16;
        size_t g = (size_t)(b * SEQ + qrow) * N3H + h * HD + l4 * 8;
        qa0 = *(const bf16x8*)(&qkvb[g]);
        qa1 = *(const bf16x8*)(&qkvb[g + 32]);
    }

    f32x4 o[4];
    #pragma unroll
    for (int dt = 0; dt < 4; ++dt) o[dt] = (f32x4){0, 0, 0, 0};
    float mrun[4] = {-1e30f, -1e30f, -1e30f, -1e30f};
    float lrun[4] = {0.f, 0.f, 0.f, 0.f};

    char* Pw = Ps + w * (16 * 128);

    for (int kt = 0; kt <= qt; ++kt) {
        __syncthreads();   // previous tile's LDS readers done
        #pragma unroll
        for (int i = 0; i < 2; ++i) {
            int lin = t + i * 256;
            int row = lin >> 3, seg = lin & 7;
            size_t gk = (size_t)(b * SEQ + kt * 64 + row) * N3H + H + h * HD + seg * 8;
            *(us8*)(Ks + row * 128 + ((seg * 16) ^ ((row & 7) << 4))) =
                *(const us8*)(&qkvb[gk]);
            size_t gv = ((size_t)((b * NH + h) * 64 + row)) * SEQ + kt * 64 + seg * 8;
            *(us8*)(Vs + row * 128 + ((seg * 16) ^ ((row & 7) << 4))) =
                *(const us8*)(&vt[gv]);
        }
        __syncthreads();

        // S = Q K^T  (4 key-subtiles of 16)
        f32x4 sv[4];
        #pragma unroll
        for (int st = 0; st < 4; ++st) {
            int krow = st * 16 + l16;
            bf16x8 kb0 = *(const bf16x8*)(Ks + krow * 128 + ((l4 * 16) ^ ((krow & 7) << 4)));
            bf16x8 kb1 = *(const bf16x8*)(Ks + krow * 128 + ((l4 * 16 + 64) ^ ((krow & 7) << 4)));
            f32x4 s = (f32x4){0, 0, 0, 0};
            s = __builtin_amdgcn_mfma_f32_16x16x32_bf16(qa0, kb0, s, 0, 0, 0);
            s = __builtin_amdgcn_mfma_f32_16x16x32_bf16(qa1, kb1, s, 0, 0, 0);
            sv[st] = s;
        }
        // scale + causal mask (diag tile only)
        #pragma unroll
        for (int st = 0; st < 4; ++st)
            #pragma unroll
            for (int j = 0; j < 4; ++j) {
                float s = sv[st][j] * 0.125f;
                if (kt == qt && (st * 16 + l16) > (w * 16 + l4 * 4 + j)) s = -3e38f;
                sv[st][j] = s;
            }

        // online softmax per q-row (16-lane groups share a row)
        float sc_[4];
        #pragma unroll
        for (int j = 0; j < 4; ++j) {
            float mx = fmaxf(fmaxf(sv[0][j], sv[1][j]), fmaxf(sv[2][j], sv[3][j]));
            mx = fmaxf(mx, __shfl_xor(mx, 1, 64));
            mx = fmaxf(mx, __shfl_xor(mx, 2, 64));
            mx = fmaxf(mx, __shfl_xor(mx, 4, 64));
            mx = fmaxf(mx, __shfl_xor(mx, 8, 64));
            float mnew = fmaxf(mrun[j], mx);
            float sc = __expf(mrun[j] - mnew);
            mrun[j] = mnew;
            float rs = 0.f;
            #pragma unroll
            for (int st = 0; st < 4; ++st) {
                float p = __expf(sv[st][j] - mnew);
                sv[st][j] = p;
                rs += p;
            }
            rs += __shfl_xor(rs, 1, 64);
            rs += __shfl_xor(rs, 2, 64);
            rs += __shfl_xor(rs, 4, 64);
            rs += __shfl_xor(rs, 8, 64);
            lrun[j] = lrun[j] * sc + rs;
            sc_[j] = sc;
        }
        #pragma unroll
        for (int dt = 0; dt < 4; ++dt)
            #pragma unroll
            for (int j = 0; j < 4; ++j) o[dt][j] *= sc_[j];

        // P (D-layout) -> per-wave LDS (A-layout source), bf16
        #pragma unroll
        for (int j = 0; j < 4; ++j) {
            int r = l4 * 4 + j;
            #pragma unroll
            for (int st = 0; st < 4; ++st) {
                int colb = (st * 16 + l16) * 2;
                *(unsigned short*)(Pw + r * 128 + (colb ^ ((r & 7) << 4))) = f2bf(sv[st][j]);
            }
        }
        // P A-frags (same-wave LDS dep; compiler inserts lgkmcnt)
        bf16x8 pa0 = *(const bf16x8*)(Pw + l16 * 128 + ((l4 * 16) ^ ((l16 & 7) << 4)));
        bf16x8 pa1 = *(const bf16x8*)(Pw + l16 * 128 + ((l4 * 16 + 64) ^ ((l16 & 7) << 4)));

        // O += P @ V   (B-operand from V^T tile)
        #pragma unroll
        for (int dt = 0; dt < 4; ++dt) {
            int vrow = dt * 16 + l16;
            bf16x8 vb0 = *(const bf16x8*)(Vs + vrow * 128 + ((l4 * 16) ^ ((vrow & 7) << 4)));
            bf16x8 vb1 = *(const bf16x8*)(Vs + vrow * 128 + ((l4 * 16 + 64) ^ ((vrow & 7) << 4)));
            o[dt] = __builtin_amdgcn_mfma_f32_16x16x32_bf16(pa0, vb0, o[dt], 0, 0, 0);
            o[dt] = __builtin_amdgcn_mfma_f32_16x16x32_bf16(pa1, vb1, o[dt], 0, 0, 0);
        }
    }

    // epilogue: normalize, write bf16 [MTOK][H]
    #pragma unroll
    for (int j = 0; j < 4; ++j) {
        float inv = 1.f / lrun[j];
        int row = b * SEQ + qt * 64 + w * 16 + l4 * 4 + j;
        #pragma unroll
        for (int dt = 0; dt < 4; ++dt)
            aout[(size_t)row * H + h * HD + dt * 16 + l16] = f2bf(o[dt][j] * inv);
    }
}

// ---------------------------------------------------------------------------
extern "C" void kernel_launch(void* const* d_in, const int* in_sizes, int n_in,
                              void* d_out, int out_size, void* d_ws, size_t ws_size,
                              hipStream_t stream) {
    const float* x      = (const float*)d_in[0];
    const float* W_qkv  = (const float*)d_in[1];
    const float* b_qkv  = (const float*)d_in[2];
    const float* W_proj = (const float*)d_in[3];
    const float* b_proj = (const float*)d_in[4];
    float* outp = (float*)d_out;

    char* ws = (char*)d_ws;
    unsigned short* xbf    = (unsigned short*)ws;                    ws += (size_t)MTOK * H * 2;
    unsigned short* wqkvT  = (unsigned short*)ws;                    ws += (size_t)N3H * H * 2;
    unsigned short* wprojT = (unsigned short*)ws;                    ws += (size_t)H * H * 2;
    unsigned short* qkvb   = (unsigned short*)ws;                    ws += (size_t)MTOK * N3H * 2;
    unsigned short* vtb    = (unsigned short*)ws;                    ws += (size_t)BSZ * NH * 64 * SEQ * 2;
    unsigned short* aob    = (unsigned short*)ws;

    // converts / transposes
    cvt_bf16<<<(MTOK * H) / (256 * 8), 256, 0, stream>>>(x, xbf, MTOK * H);
    tconv_bf16<<<dim3(N3H / 64, H / 64), 256, 0, stream>>>(W_qkv, wqkvT, H, N3H);
    tconv_bf16<<<dim3(H / 64, H / 64), 256, 0, stream>>>(W_proj, wprojT, H, H);

    // QKV: [16384,768] @ [768,2304] -> bf16
    gemm_bf16<<<dim3(N3H / 128, MTOK / 128), 256, 0, stream>>>(
        xbf, wqkvT, b_qkv, qkvb, MTOK, N3H, H, 0);

    // V transpose per (b,h)
    vtrans<<<dim3(SEQ / 64, NH, BSZ), 256, 0, stream>>>(qkvb, vtb);

    // attention
    attn_mfma<<<dim3(SEQ / 64, NH, BSZ), 256, 0, stream>>>(qkvb, vtb, aob);

    // proj: [16384,768] @ [768,768] -> fp32 out
    gemm_bf16<<<dim3(H / 128, MTOK / 128), 256, 0, stream>>>(
        aob, wprojT, b_proj, (void*)outp, MTOK, H, H, 1);
}

// Round 3
// 366.705 us; speedup vs baseline: 6.5258x; 1.0828x over previous
//
#include <hip/hip_runtime.h>

#define H 768
#define NH 12
#define HD 64
#define BSZ 16
#define SEQ 1024
#define MTOK (BSZ * SEQ)   // 16384
#define N3H (3 * H)        // 2304

typedef __attribute__((ext_vector_type(8))) short bf16x8;
typedef __attribute__((ext_vector_type(4))) float f32x4;
typedef __attribute__((ext_vector_type(8))) unsigned short us8;
typedef __attribute__((ext_vector_type(4))) unsigned short us4;

__device__ __forceinline__ unsigned short f2bf(float f) {
    union { float f; unsigned u; } v; v.f = f;
    unsigned r = v.u + 0x7fffu + ((v.u >> 16) & 1u);   // RNE
    return (unsigned short)(r >> 16);
}

typedef __attribute__((address_space(1))) const unsigned int gu32_t;
typedef __attribute__((address_space(3))) unsigned int lu32_t;
__device__ __forceinline__ void glds16(const void* g, void* l) {
    __builtin_amdgcn_global_load_lds((gu32_t*)g, (lu32_t*)l, 16, 0, 0);
}

// ---------------------------------------------------------------------------
// fp32 -> bf16 elementwise convert (n multiple of 8)
// ---------------------------------------------------------------------------
__global__ __launch_bounds__(256) void cvt_bf16(
    const float* __restrict__ in, unsigned short* __restrict__ out, int n)
{
    int i = (blockIdx.x * 256 + threadIdx.x) * 8;
    if (i >= n) return;
    float4 a = *(const float4*)(in + i);
    float4 b = *(const float4*)(in + i + 4);
    us8 o;
    o[0]=f2bf(a.x); o[1]=f2bf(a.y); o[2]=f2bf(a.z); o[3]=f2bf(a.w);
    o[4]=f2bf(b.x); o[5]=f2bf(b.y); o[6]=f2bf(b.z); o[7]=f2bf(b.w);
    *(us8*)(out + i) = o;
}

// ---------------------------------------------------------------------------
// fp32 [Kd][Nd] -> bf16 transposed [Nd][Kd]  (64x64 LDS tiles)
// ---------------------------------------------------------------------------
__global__ __launch_bounds__(256) void tconv_bf16(
    const float* __restrict__ in, unsigned short* __restrict__ out, int Kd, int Nd)
{
    __shared__ float tile[64][65];
    int t = threadIdx.x;
    int n0 = blockIdx.x * 64, k0 = blockIdx.y * 64;
    #pragma unroll
    for (int r = 0; r < 4; ++r) {
        int kl = r * 16 + (t >> 4);
        float4 v = *(const float4*)(&in[(size_t)(k0 + kl) * Nd + n0 + (t & 15) * 4]);
        tile[kl][(t & 15) * 4 + 0] = v.x; tile[kl][(t & 15) * 4 + 1] = v.y;
        tile[kl][(t & 15) * 4 + 2] = v.z; tile[kl][(t & 15) * 4 + 3] = v.w;
    }
    __syncthreads();
    int nl = t >> 2, kc = (t & 3) * 16;
    us8 o0, o1;
    #pragma unroll
    for (int kk = 0; kk < 8; ++kk) o0[kk] = f2bf(tile[kc + kk][nl]);
    #pragma unroll
    for (int kk = 0; kk < 8; ++kk) o1[kk] = f2bf(tile[kc + 8 + kk][nl]);
    size_t ob = (size_t)(n0 + nl) * Kd + k0 + kc;
    *(us8*)(&out[ob]) = o0;
    *(us8*)(&out[ob + 8]) = o1;
}

// ---------------------------------------------------------------------------
// bf16 MFMA GEMM: C[M,N] = A[M,K] @ BT[N,K]^T + bias
// 128x128 tile, BK=64, 4 waves. global_load_lds(16B) staging with
// pre-swizzled source; swizzled ds_read_b128; m97 structure.
// ---------------------------------------------------------------------------
__global__ __launch_bounds__(256) void gemm_bf16(
    const unsigned short* __restrict__ A, const unsigned short* __restrict__ BT,
    const float* __restrict__ bias, void* __restrict__ Cout,
    int M, int N, int K, int write_f32)
{
    __shared__ char lds[32768];
    char* As = lds;
    char* Bs = lds + 16384;
    const char* Ac = (const char*)A;
    const char* Bc = (const char*)BT;
    int t = threadIdx.x;
    int l = t & 63, w = t >> 6;
    int l16 = l & 15, l4 = l >> 4;
    int wm = w >> 1, wn = w & 1;
    int rowBase = blockIdx.y * 128, colBase = blockIdx.x * 128;

    f32x4 acc[4][4];
    #pragma unroll
    for (int i = 0; i < 4; ++i)
        #pragma unroll
        for (int j = 0; j < 4; ++j) acc[i][j] = (f32x4){0, 0, 0, 0};

    for (int k0 = 0; k0 < K; k0 += 64) {
        #pragma unroll
        for (int i = 0; i < 4; ++i) {
            int c = t + i * 256;             // 0..1023
            int row = c >> 3;
            int src = ((c & 7) * 16) ^ ((row & 7) << 4);
            glds16(Ac + ((size_t)(rowBase + row) * K + k0) * 2 + src, As + c * 16);
            glds16(Bc + ((size_t)(colBase + row) * K + k0) * 2 + src, Bs + c * 16);
        }
        asm volatile("s_waitcnt vmcnt(0)" ::: "memory");
        __builtin_amdgcn_s_barrier();

        #pragma unroll
        for (int kh = 0; kh < 2; ++kh) {
            bf16x8 af[4], bfr[4];
            #pragma unroll
            for (int mi = 0; mi < 4; ++mi) {
                int row = wm * 64 + mi * 16 + l16;
                af[mi] = *(const bf16x8*)(As + row * 128 + ((l4 * 16 + kh * 64) ^ ((row & 7) << 4)));
            }
            #pragma unroll
            for (int ni = 0; ni < 4; ++ni) {
                int row = wn * 64 + ni * 16 + l16;
                bfr[ni] = *(const bf16x8*)(Bs + row * 128 + ((l4 * 16 + kh * 64) ^ ((row & 7) << 4)));
            }
            #pragma unroll
            for (int mi = 0; mi < 4; ++mi)
                #pragma unroll
                for (int ni = 0; ni < 4; ++ni)
                    acc[mi][ni] = __builtin_amdgcn_mfma_f32_16x16x32_bf16(
                        af[mi], bfr[ni], acc[mi][ni], 0, 0, 0);
        }
        __builtin_amdgcn_s_barrier();
    }

    #pragma unroll
    for (int ni = 0; ni < 4; ++ni) {
        int col = colBase + wn * 64 + ni * 16 + l16;
        float bb = bias ? bias[col] : 0.f;
        #pragma unroll
        for (int mi = 0; mi < 4; ++mi) {
            #pragma unroll
            for (int j = 0; j < 4; ++j) {
                int row = rowBase + wm * 64 + mi * 16 + l4 * 4 + j;
                float v = acc[mi][ni][j] + bb;
                if (write_f32) ((float*)Cout)[(size_t)row * N + col] = v;
                else ((unsigned short*)Cout)[(size_t)row * N + col] = f2bf(v);
            }
        }
    }
}

// ---------------------------------------------------------------------------
// V transpose: qkv bf16 [MTOK][2304] (V part) -> vt bf16 [b][h][d=64][s=1024]
// ---------------------------------------------------------------------------
__global__ __launch_bounds__(256) void vtrans(
    const unsigned short* __restrict__ qkvb, unsigned short* __restrict__ vt)
{
    __shared__ char tile[64 * 128];
    int t = threadIdx.x;
    int st = blockIdx.x, h = blockIdx.y, b = blockIdx.z;
    int s0 = st * 64;
    {
        int s = t >> 2, dc = (t & 3) * 16;
        size_t g = (size_t)(b * SEQ + s0 + s) * N3H + 2 * H + h * HD + dc;
        us8 v0 = *(const us8*)(&qkvb[g]);
        us8 v1 = *(const us8*)(&qkvb[g + 8]);
        *(us8*)(tile + s * 128 + ((dc * 2) ^ ((s & 7) << 4))) = v0;
        *(us8*)(tile + s * 128 + ((dc * 2 + 16) ^ ((s & 7) << 4))) = v1;
    }
    __syncthreads();
    int d = t >> 2, sc = (t & 3) * 16;
    us8 o0, o1;
    #pragma unroll
    for (int kk = 0; kk < 8; ++kk) {
        int s = sc + kk;
        o0[kk] = *(const unsigned short*)(tile + s * 128 + ((d * 2) ^ ((s & 7) << 4)));
    }
    #pragma unroll
    for (int kk = 0; kk < 8; ++kk) {
        int s = sc + 8 + kk;
        o1[kk] = *(const unsigned short*)(tile + s * 128 + ((d * 2) ^ ((s & 7) << 4)));
    }
    size_t ob = ((size_t)((b * NH + h) * 64 + d)) * SEQ + s0 + sc;
    *(us8*)(&vt[ob]) = o0;
    *(us8*)(&vt[ob + 8]) = o1;
}

// ---------------------------------------------------------------------------
// Flash attention v2: swapped QK^T (S^T = K·Q^T), 4 waves x 32 q-rows,
// K/V double-buffered via global_load_lds(16) w/ pre-swizzled source,
// counted vmcnt(4), raw barriers. Per-wave P bounce (b64 writes/b128 reads).
// ---------------------------------------------------------------------------
__global__ __launch_bounds__(256) void attn_mfma(
    const unsigned short* __restrict__ qkvb,
    const unsigned short* __restrict__ vt,
    unsigned short* __restrict__ aout)
{
    __shared__ char lds[49152];          // K db 16K | V db 16K | P 16K
    char* Kbuf = lds;
    char* Vbuf = lds + 16384;
    int t = threadIdx.x;
    int l = t & 63, w = t >> 6;
    int l16 = l & 15, l4 = l >> 4;
    int qb = blockIdx.x, h = blockIdx.y, b = blockIdx.z;
    int wqbase = qb * 128 + w * 32;
    int bh = b * NH + h;
    char* Pw = lds + 32768 + w * 4096;   // [32 rows][128 B]
    int nt = 2 * qb + 2;
    int sw = (l16 & 7) << 4;

    const char* qkvc = (const char*)qkvb;
    const char* vtc  = (const char*)vt;

    // Q as B-fragments (col = q = l16, k = d = l4*8+j)
    bf16x8 qB[2][2];
    #pragma unroll
    for (int qs = 0; qs < 2; ++qs) {
        size_t tok = (size_t)(b * SEQ + wqbase + qs * 16 + l16);
        const unsigned short* qrow = qkvb + tok * N3H + h * HD + l4 * 8;
        qB[qs][0] = *(const bf16x8*)(qrow);
        qB[qs][1] = *(const bf16x8*)(qrow + 32);
    }

    auto STAGE = [&](int kt, int bi) {
        #pragma unroll
        for (int i = 0; i < 2; ++i) {
            int c = t + i * 256;
            int row = c >> 3;
            int src = ((c & 7) * 16) ^ ((row & 7) << 4);
            glds16(qkvc + ((size_t)(b * SEQ + kt * 64 + row) * N3H + H + h * HD) * 2 + src,
                   Kbuf + bi * 8192 + c * 16);
        }
        #pragma unroll
        for (int i = 0; i < 2; ++i) {
            int c = t + i * 256;
            int row = c >> 3;
            int src = ((c & 7) * 16) ^ ((row & 7) << 4);
            glds16(vtc + (((size_t)(bh * 64 + row)) * SEQ + kt * 64) * 2 + src,
                   Vbuf + bi * 8192 + c * 16);
        }
    };

    STAGE(0, 0);
    __syncthreads();   // drain Q loads + stage0; clean vmcnt state

    f32x4 o[2][4];
    #pragma unroll
    for (int qs = 0; qs < 2; ++qs)
        #pragma unroll
        for (int dt = 0; dt < 4; ++dt) o[qs][dt] = (f32x4){0, 0, 0, 0};
    float mrun[2] = {-1e30f, -1e30f};
    float lrun[2] = {0.f, 0.f};

    for (int kt = 0; kt < nt; ++kt) {
        int bi = kt & 1;
        if (kt + 1 < nt) {
            STAGE(kt + 1, bi ^ 1);
            asm volatile("s_waitcnt vmcnt(4)" ::: "memory");
        } else {
            asm volatile("s_waitcnt vmcnt(0)" ::: "memory");
        }
        __builtin_amdgcn_s_barrier();

        int ktbase = kt * 64;
        if (ktbase <= wqbase + 31) {       // wave has unmasked work this tile
            const char* Kb = Kbuf + bi * 8192;
            const char* Vb = Vbuf + bi * 8192;

            // K as A-fragments (row = key = l16 within subtile, k = d)
            bf16x8 kf[4][2];
            #pragma unroll
            for (int st = 0; st < 4; ++st) {
                int row = st * 16 + l16;
                kf[st][0] = *(const bf16x8*)(Kb + row * 128 + ((l4 * 16) ^ sw));
                kf[st][1] = *(const bf16x8*)(Kb + row * 128 + ((l4 * 16 + 64) ^ sw));
            }

            // S^T = K Q^T : D rows = keys, cols = q
            f32x4 sv[2][4];
            #pragma unroll
            for (int qs = 0; qs < 2; ++qs)
                #pragma unroll
                for (int st = 0; st < 4; ++st) {
                    f32x4 s = (f32x4){0, 0, 0, 0};
                    s = __builtin_amdgcn_mfma_f32_16x16x32_bf16(kf[st][0], qB[qs][0], s, 0, 0, 0);
                    s = __builtin_amdgcn_mfma_f32_16x16x32_bf16(kf[st][1], qB[qs][1], s, 0, 0, 0);
                    sv[qs][st] = s;
                }

            if (ktbase + 63 > wqbase) {    // causal mask needed
                #pragma unroll
                for (int qs = 0; qs < 2; ++qs) {
                    int q = wqbase + qs * 16 + l16;
                    #pragma unroll
                    for (int st = 0; st < 4; ++st)
                        #pragma unroll
                        for (int r = 0; r < 4; ++r) {
                            int key = ktbase + st * 16 + l4 * 4 + r;
                            if (key > q) sv[qs][st][r] = -3e38f;
                        }
                }
            }

            // online softmax (row = q, lane-local over 16 keys + 2 shuffles)
            #pragma unroll
            for (int qs = 0; qs < 2; ++qs) {
                float mx = sv[qs][0][0];
                #pragma unroll
                for (int st = 0; st < 4; ++st)
                    #pragma unroll
                    for (int r = 0; r < 4; ++r) mx = fmaxf(mx, sv[qs][st][r]);
                mx = fmaxf(mx, __shfl_xor(mx, 16, 64));
                mx = fmaxf(mx, __shfl_xor(mx, 32, 64));
                float mnew = fmaxf(mrun[qs], mx * 0.125f);
                float sc = __expf(mrun[qs] - mnew);
                mrun[qs] = mnew;
                float rs = 0.f;
                #pragma unroll
                for (int st = 0; st < 4; ++st)
                    #pragma unroll
                    for (int r = 0; r < 4; ++r) {
                        float p = __expf(fmaf(sv[qs][st][r], 0.125f, -mnew));
                        sv[qs][st][r] = p;
                        rs += p;
                    }
                rs += __shfl_xor(rs, 16, 64);
                rs += __shfl_xor(rs, 32, 64);
                lrun[qs] = lrun[qs] * sc + rs;
                #pragma unroll
                for (int dt = 0; dt < 4; ++dt) {
                    o[qs][dt][0] *= sc; o[qs][dt][1] *= sc;
                    o[qs][dt][2] *= sc; o[qs][dt][3] *= sc;
                }
            }

            // P -> per-wave LDS as [q row][key] bf16 (b64 writes)
            #pragma unroll
            for (int qs = 0; qs < 2; ++qs) {
                int row = qs * 16 + l16;
                #pragma unroll
                for (int st = 0; st < 4; ++st) {
                    us4 pk;
                    #pragma unroll
                    for (int r = 0; r < 4; ++r) pk[r] = f2bf(sv[qs][st][r]);
                    *(us4*)(Pw + row * 128 + ((st * 32 + l4 * 8) ^ sw)) = pk;
                }
            }
            // P as B-fragments (col = q = l16, k = key)
            bf16x8 pB[2][2];
            #pragma unroll
            for (int qs = 0; qs < 2; ++qs) {
                int row = qs * 16 + l16;
                pB[qs][0] = *(const bf16x8*)(Pw + row * 128 + ((l4 * 16) ^ sw));
                pB[qs][1] = *(const bf16x8*)(Pw + row * 128 + ((l4 * 16 + 64) ^ sw));
            }

            // O^T += V^T P^T : A = V^T (rows = d), B = P (cols = q)
            #pragma unroll
            for (int dt = 0; dt < 4; ++dt) {
                int row = dt * 16 + l16;
                bf16x8 v0 = *(const bf16x8*)(Vb + row * 128 + ((l4 * 16) ^ sw));
                bf16x8 v1 = *(const bf16x8*)(Vb + row * 128 + ((l4 * 16 + 64) ^ sw));
                #pragma unroll
                for (int qs = 0; qs < 2; ++qs) {
                    o[qs][dt] = __builtin_amdgcn_mfma_f32_16x16x32_bf16(v0, pB[qs][0], o[qs][dt], 0, 0, 0);
                    o[qs][dt] = __builtin_amdgcn_mfma_f32_16x16x32_bf16(v1, pB[qs][1], o[qs][dt], 0, 0, 0);
                }
            }
        }
        __builtin_amdgcn_s_barrier();
    }

    // epilogue: O^T cols = q (l16), rows = d; normalize, write bf16 [MTOK][H]
    #pragma unroll
    for (int qs = 0; qs < 2; ++qs) {
        float inv = 1.f / lrun[qs];
        size_t tok = (size_t)(b * SEQ + wqbase + qs * 16 + l16);
        #pragma unroll
        for (int dt = 0; dt < 4; ++dt) {
            us4 ov;
            #pragma unroll
            for (int r = 0; r < 4; ++r) ov[r] = f2bf(o[qs][dt][r] * inv);
            *(us4*)(&aout[tok * H + h * HD + dt * 16 + l4 * 4]) = ov;
        }
    }
}

// ---------------------------------------------------------------------------
extern "C" void kernel_launch(void* const* d_in, const int* in_sizes, int n_in,
                              void* d_out, int out_size, void* d_ws, size_t ws_size,
                              hipStream_t stream) {
    const float* x      = (const float*)d_in[0];
    const float* W_qkv  = (const float*)d_in[1];
    const float* b_qkv  = (const float*)d_in[2];
    const float* W_proj = (const float*)d_in[3];
    const float* b_proj = (const float*)d_in[4];
    float* outp = (float*)d_out;

    char* ws = (char*)d_ws;
    unsigned short* xbf    = (unsigned short*)ws;  ws += (size_t)MTOK * H * 2;
    unsigned short* wqkvT  = (unsigned short*)ws;  ws += (size_t)N3H * H * 2;
    unsigned short* wprojT = (unsigned short*)ws;  ws += (size_t)H * H * 2;
    unsigned short* qkvb   = (unsigned short*)ws;  ws += (size_t)MTOK * N3H * 2;
    unsigned short* vtb    = (unsigned short*)ws;  ws += (size_t)BSZ * NH * 64 * SEQ * 2;
    unsigned short* aob    = (unsigned short*)ws;

    cvt_bf16<<<(MTOK * H) / (256 * 8), 256, 0, stream>>>(x, xbf, MTOK * H);
    tconv_bf16<<<dim3(N3H / 64, H / 64), 256, 0, stream>>>(W_qkv, wqkvT, H, N3H);
    tconv_bf16<<<dim3(H / 64, H / 64), 256, 0, stream>>>(W_proj, wprojT, H, H);

    gemm_bf16<<<dim3(N3H / 128, MTOK / 128), 256, 0, stream>>>(
        xbf, wqkvT, b_qkv, qkvb, MTOK, N3H, H, 0);

    vtrans<<<dim3(SEQ / 64, NH, BSZ), 256, 0, stream>>>(qkvb, vtb);

    attn_mfma<<<dim3(SEQ / 128, NH, BSZ), 256, 0, stream>>>(qkvb, vtb, aob);

    gemm_bf16<<<dim3(H / 128, MTOK / 128), 256, 0, stream>>>(
        aob, wprojT, b_proj, (void*)outp, MTOK, H, H, 1);
}

// Round 4
// 317.756 us; speedup vs baseline: 7.5311x; 1.1540x over previous
//
#include <hip/hip_runtime.h>

#define H 768
#define NH 12
#define HD 64
#define BSZ 16
#define SEQ 1024
#define MTOK (BSZ * SEQ)   // 16384
#define N3H (3 * H)        // 2304

typedef __attribute__((ext_vector_type(8))) short bf16x8;
typedef __attribute__((ext_vector_type(4))) float f32x4;
typedef __attribute__((ext_vector_type(16))) float f32x16;
typedef __attribute__((ext_vector_type(8))) unsigned short us8;
typedef __attribute__((ext_vector_type(4))) unsigned short us4;

__device__ __forceinline__ unsigned short f2bf(float f) {
    union { float f; unsigned u; } v; v.f = f;
    unsigned r = v.u + 0x7fffu + ((v.u >> 16) & 1u);   // RNE
    return (unsigned short)(r >> 16);
}

typedef __attribute__((address_space(1))) const unsigned int gu32_t;
typedef __attribute__((address_space(3))) unsigned int lu32_t;
__device__ __forceinline__ void glds16(const void* g, void* l) {
    __builtin_amdgcn_global_load_lds((gu32_t*)g, (lu32_t*)l, 16, 0, 0);
}

// ---------------------------------------------------------------------------
// fp32 -> bf16 elementwise convert (n multiple of 8)
// ---------------------------------------------------------------------------
__global__ __launch_bounds__(256) void cvt_bf16(
    const float* __restrict__ in, unsigned short* __restrict__ out, int n)
{
    int i = (blockIdx.x * 256 + threadIdx.x) * 8;
    if (i >= n) return;
    float4 a = *(const float4*)(in + i);
    float4 b = *(const float4*)(in + i + 4);
    us8 o;
    o[0]=f2bf(a.x); o[1]=f2bf(a.y); o[2]=f2bf(a.z); o[3]=f2bf(a.w);
    o[4]=f2bf(b.x); o[5]=f2bf(b.y); o[6]=f2bf(b.z); o[7]=f2bf(b.w);
    *(us8*)(out + i) = o;
}

// ---------------------------------------------------------------------------
// fp32 [Kd][Nd] -> bf16 transposed [Nd][Kd]  (64x64 LDS tiles)
// ---------------------------------------------------------------------------
__global__ __launch_bounds__(256) void tconv_bf16(
    const float* __restrict__ in, unsigned short* __restrict__ out, int Kd, int Nd)
{
    __shared__ float tile[64][65];
    int t = threadIdx.x;
    int n0 = blockIdx.x * 64, k0 = blockIdx.y * 64;
    #pragma unroll
    for (int r = 0; r < 4; ++r) {
        int kl = r * 16 + (t >> 4);
        float4 v = *(const float4*)(&in[(size_t)(k0 + kl) * Nd + n0 + (t & 15) * 4]);
        tile[kl][(t & 15) * 4 + 0] = v.x; tile[kl][(t & 15) * 4 + 1] = v.y;
        tile[kl][(t & 15) * 4 + 2] = v.z; tile[kl][(t & 15) * 4 + 3] = v.w;
    }
    __syncthreads();
    int nl = t >> 2, kc = (t & 3) * 16;
    us8 o0, o1;
    #pragma unroll
    for (int kk = 0; kk < 8; ++kk) o0[kk] = f2bf(tile[kc + kk][nl]);
    #pragma unroll
    for (int kk = 0; kk < 8; ++kk) o1[kk] = f2bf(tile[kc + 8 + kk][nl]);
    size_t ob = (size_t)(n0 + nl) * Kd + k0 + kc;
    *(us8*)(&out[ob]) = o0;
    *(us8*)(&out[ob + 8]) = o1;
}

// ---------------------------------------------------------------------------
// bf16 MFMA GEMM: C[M,N] = A[M,K] @ BT[N,K]^T + bias
// 128x128 tile, BK=64, 4 waves. global_load_lds(16B) staging with
// pre-swizzled source; swizzled ds_read_b128; m97 structure. 1D grid with
// bijective XCD chunk swizzle (grid % 8 == 0 guaranteed by caller).
// ---------------------------------------------------------------------------
__global__ __launch_bounds__(256) void gemm_bf16(
    const unsigned short* __restrict__ A, const unsigned short* __restrict__ BT,
    const float* __restrict__ bias, void* __restrict__ Cout,
    int M, int N, int K, int write_f32)
{
    __shared__ char lds[32768];
    char* As = lds;
    char* Bs = lds + 16384;
    const char* Ac = (const char*)A;
    const char* Bc = (const char*)BT;
    int t = threadIdx.x;
    int l = t & 63, w = t >> 6;
    int l16 = l & 15, l4 = l >> 4;
    int wm = w >> 1, wn = w & 1;

    int chunk = (int)gridDim.x >> 3;
    int lin = (blockIdx.x & 7) * chunk + (blockIdx.x >> 3);
    int nbx = N >> 7;
    int bx = lin % nbx, by = lin / nbx;
    int rowBase = by * 128, colBase = bx * 128;

    f32x4 acc[4][4];
    #pragma unroll
    for (int i = 0; i < 4; ++i)
        #pragma unroll
        for (int j = 0; j < 4; ++j) acc[i][j] = (f32x4){0, 0, 0, 0};

    for (int k0 = 0; k0 < K; k0 += 64) {
        #pragma unroll
        for (int i = 0; i < 4; ++i) {
            int c = t + i * 256;             // 0..1023
            int row = c >> 3;
            int src = ((c & 7) * 16) ^ ((row & 7) << 4);
            glds16(Ac + ((size_t)(rowBase + row) * K + k0) * 2 + src, As + c * 16);
            glds16(Bc + ((size_t)(colBase + row) * K + k0) * 2 + src, Bs + c * 16);
        }
        asm volatile("s_waitcnt vmcnt(0)" ::: "memory");
        __builtin_amdgcn_s_barrier();

        #pragma unroll
        for (int kh = 0; kh < 2; ++kh) {
            bf16x8 af[4], bfr[4];
            #pragma unroll
            for (int mi = 0; mi < 4; ++mi) {
                int row = wm * 64 + mi * 16 + l16;
                af[mi] = *(const bf16x8*)(As + row * 128 + ((l4 * 16 + kh * 64) ^ ((row & 7) << 4)));
            }
            #pragma unroll
            for (int ni = 0; ni < 4; ++ni) {
                int row = wn * 64 + ni * 16 + l16;
                bfr[ni] = *(const bf16x8*)(Bs + row * 128 + ((l4 * 16 + kh * 64) ^ ((row & 7) << 4)));
            }
            #pragma unroll
            for (int mi = 0; mi < 4; ++mi)
                #pragma unroll
                for (int ni = 0; ni < 4; ++ni)
                    acc[mi][ni] = __builtin_amdgcn_mfma_f32_16x16x32_bf16(
                        af[mi], bfr[ni], acc[mi][ni], 0, 0, 0);
        }
        __builtin_amdgcn_s_barrier();
    }

    #pragma unroll
    for (int ni = 0; ni < 4; ++ni) {
        int col = colBase + wn * 64 + ni * 16 + l16;
        float bb = bias ? bias[col] : 0.f;
        #pragma unroll
        for (int mi = 0; mi < 4; ++mi) {
            #pragma unroll
            for (int j = 0; j < 4; ++j) {
                int row = rowBase + wm * 64 + mi * 16 + l4 * 4 + j;
                float v = acc[mi][ni][j] + bb;
                if (write_f32) ((float*)Cout)[(size_t)row * N + col] = v;
                else ((unsigned short*)Cout)[(size_t)row * N + col] = f2bf(v);
            }
        }
    }
}

// ---------------------------------------------------------------------------
// V transpose: qkv bf16 [MTOK][2304] (V part) -> vt bf16 [b][h][d=64][s=1024]
// ---------------------------------------------------------------------------
__global__ __launch_bounds__(256) void vtrans(
    const unsigned short* __restrict__ qkvb, unsigned short* __restrict__ vt)
{
    __shared__ char tile[64 * 128];
    int t = threadIdx.x;
    int st = blockIdx.x, h = blockIdx.y, b = blockIdx.z;
    int s0 = st * 64;
    {
        int s = t >> 2, dc = (t & 3) * 16;
        size_t g = (size_t)(b * SEQ + s0 + s) * N3H + 2 * H + h * HD + dc;
        us8 v0 = *(const us8*)(&qkvb[g]);
        us8 v1 = *(const us8*)(&qkvb[g + 8]);
        *(us8*)(tile + s * 128 + ((dc * 2) ^ ((s & 7) << 4))) = v0;
        *(us8*)(tile + s * 128 + ((dc * 2 + 16) ^ ((s & 7) << 4))) = v1;
    }
    __syncthreads();
    int d = t >> 2, sc = (t & 3) * 16;
    us8 o0, o1;
    #pragma unroll
    for (int kk = 0; kk < 8; ++kk) {
        int s = sc + kk;
        o0[kk] = *(const unsigned short*)(tile + s * 128 + ((d * 2) ^ ((s & 7) << 4)));
    }
    #pragma unroll
    for (int kk = 0; kk < 8; ++kk) {
        int s = sc + 8 + kk;
        o1[kk] = *(const unsigned short*)(tile + s * 128 + ((d * 2) ^ ((s & 7) << 4)));
    }
    size_t ob = ((size_t)((b * NH + h) * 64 + d)) * SEQ + s0 + sc;
    *(us8*)(&vt[ob]) = o0;
    *(us8*)(&vt[ob + 8]) = o1;
}

// ---------------------------------------------------------------------------
// Flash attention v3: 32x32x16 MFMA. 4 waves x 32 q each (128 q/block).
// Swapped QK^T (S^T = K·Q^T): lane holds col q = l&31, rows = keys.
// In-register P re-layout via one shfl_xor(32) per 16-key window (no P LDS).
// K/V double-buffered via global_load_lds(16) w/ pre-swizzled source,
// counted vmcnt(4). XCD-chunk swizzle + heavy-qb-first on 1D grid.
// ---------------------------------------------------------------------------
__global__ __launch_bounds__(256, 4) void attn_mfma(
    const unsigned short* __restrict__ qkvb,
    const unsigned short* __restrict__ vt,
    unsigned short* __restrict__ aout)
{
    __shared__ char lds[32768];          // K dbuf 2x8K | V dbuf 2x8K
    char* Kbuf = lds;
    char* Vbuf = lds + 16384;
    int t = threadIdx.x;
    int l = t & 63, w = t >> 6;
    int l31 = l & 31, b5 = l >> 5;

    int lin = ((blockIdx.x & 7) * 192) + (blockIdx.x >> 3);   // XCD chunks
    int qb = 7 - (lin & 7);                                   // heavy first
    int bh = lin >> 3;
    int h = bh % NH, b = bh / NH;

    int wq = qb * 128 + w * 32;          // wave's 32 q rows
    int sw31 = (l31 & 7) << 4;
    int nt = 2 * qb + 2;
    int bhh = b * NH + h;
    const char* qkvc = (const char*)qkvb;
    const char* vtc  = (const char*)vt;

    // Q as B-fragments: col = q = l31, k = d = 16m + b5*8 + j
    bf16x8 qB[4];
    {
        const unsigned short* qrow =
            qkvb + (size_t)(b * SEQ + wq + l31) * N3H + h * HD + b5 * 8;
        #pragma unroll
        for (int m = 0; m < 4; ++m) qB[m] = *(const bf16x8*)(qrow + m * 16);
    }

    auto STAGE = [&](int kt, int bi) {
        #pragma unroll
        for (int i = 0; i < 2; ++i) {
            int c = t + i * 256;
            int row = c >> 3;
            int src = ((c & 7) * 16) ^ ((row & 7) << 4);
            glds16(qkvc + ((size_t)(b * SEQ + kt * 64 + row) * N3H + H + h * HD) * 2 + src,
                   Kbuf + bi * 8192 + c * 16);
        }
        #pragma unroll
        for (int i = 0; i < 2; ++i) {
            int c = t + i * 256;
            int row = c >> 3;
            int src = ((c & 7) * 16) ^ ((row & 7) << 4);
            glds16(vtc + (((size_t)(bhh * 64 + row)) * SEQ + kt * 64) * 2 + src,
                   Vbuf + bi * 8192 + c * 16);
        }
    };

    STAGE(0, 0);
    __syncthreads();   // drains all vmem (Q regs + stage0); clean vmcnt state

    f32x16 o0, o1;
    #pragma unroll
    for (int r = 0; r < 16; ++r) { o0[r] = 0.f; o1[r] = 0.f; }
    float mrun = -1e30f, lrun = 0.f;

    for (int kt = 0; kt < nt; ++kt) {
        int bi = kt & 1;
        if (kt + 1 < nt) {
            STAGE(kt + 1, bi ^ 1);
            asm volatile("s_waitcnt vmcnt(4)" ::: "memory");
        } else {
            asm volatile("s_waitcnt vmcnt(0)" ::: "memory");
        }
        __builtin_amdgcn_s_barrier();

        int ktbase = kt * 64;
        if (ktbase <= wq + 31) {          // wave has unmasked work
            const char* Kb = Kbuf + bi * 8192;
            const char* Vb = Vbuf + bi * 8192;

            // S^T = K·Q^T : D rows = keys ((r&3)+8*(r>>2)+4*b5), cols = q
            f32x16 s[2];
            __builtin_amdgcn_s_setprio(1);
            #pragma unroll
            for (int st2 = 0; st2 < 2; ++st2) {
                f32x16 acc;
                #pragma unroll
                for (int r = 0; r < 16; ++r) acc[r] = 0.f;
                #pragma unroll
                for (int m = 0; m < 4; ++m) {
                    int row = st2 * 32 + l31;
                    bf16x8 kf = *(const bf16x8*)(Kb + row * 128 + ((m * 32 + b5 * 16) ^ sw31));
                    acc = __builtin_amdgcn_mfma_f32_32x32x16_bf16(kf, qB[m], acc, 0, 0, 0);
                }
                s[st2] = acc;
            }
            __builtin_amdgcn_s_setprio(0);

            if (ktbase + 63 > wq) {       // causal mask needed
                int q = wq + l31;
                #pragma unroll
                for (int st2 = 0; st2 < 2; ++st2)
                    #pragma unroll
                    for (int r = 0; r < 16; ++r) {
                        int key = ktbase + st2 * 32 + (r & 3) + 8 * (r >> 2) + 4 * b5;
                        if (key > q) s[st2][r] = -3e38f;
                    }
            }

            // online softmax per q col: 31 in-lane + 1 xor32 shuffle
            float mx = s[0][0];
            #pragma unroll
            for (int r = 1; r < 16; ++r) mx = fmaxf(mx, s[0][r]);
            #pragma unroll
            for (int r = 0; r < 16; ++r) mx = fmaxf(mx, s[1][r]);
            mx = fmaxf(mx, __shfl_xor(mx, 32, 64));
            float mnew = fmaxf(mrun, mx * 0.125f);
            float sc = __expf(mrun - mnew);
            mrun = mnew;
            float rs = 0.f;
            #pragma unroll
            for (int st2 = 0; st2 < 2; ++st2)
                #pragma unroll
                for (int r = 0; r < 16; ++r) {
                    float p = __expf(fmaf(s[st2][r], 0.125f, -mnew));
                    s[st2][r] = p;
                    rs += p;
                }
            rs += __shfl_xor(rs, 32, 64);
            lrun = lrun * sc + rs;
            #pragma unroll
            for (int r = 0; r < 16; ++r) { o0[r] *= sc; o1[r] *= sc; }

            // P D-layout -> B-fragments, in-register (1 xor32 swap / window)
            // window wd keys: b5=0 holds {0-3,8-11}, b5=1 holds {4-7,12-15}
            bf16x8 pB[4];
            #pragma unroll
            for (int wd = 0; wd < 4; ++wd) {
                int st2 = wd >> 1, hf = (wd & 1) * 8;
                unsigned pk0 = (unsigned)f2bf(s[st2][hf + 0]) | ((unsigned)f2bf(s[st2][hf + 1]) << 16);
                unsigned pk1 = (unsigned)f2bf(s[st2][hf + 2]) | ((unsigned)f2bf(s[st2][hf + 3]) << 16);
                unsigned pk2 = (unsigned)f2bf(s[st2][hf + 4]) | ((unsigned)f2bf(s[st2][hf + 5]) << 16);
                unsigned pk3 = (unsigned)f2bf(s[st2][hf + 6]) | ((unsigned)f2bf(s[st2][hf + 7]) << 16);
                unsigned snd0 = b5 ? pk0 : pk2;
                unsigned snd1 = b5 ? pk1 : pk3;
                unsigned r0 = (unsigned)__shfl_xor((int)snd0, 32, 64);
                unsigned r1 = (unsigned)__shfl_xor((int)snd1, 32, 64);
                union { unsigned u[4]; bf16x8 v; } cvt;
                cvt.u[0] = b5 ? r0 : pk0;
                cvt.u[1] = b5 ? r1 : pk1;
                cvt.u[2] = b5 ? pk2 : r0;
                cvt.u[3] = b5 ? pk3 : r1;
                pB[wd] = cvt.v;
            }

            // O^T += V^T · P^T : A = V^T (rows = d), B = P (cols = q)
            __builtin_amdgcn_s_setprio(1);
            #pragma unroll
            for (int wd = 0; wd < 4; ++wd) {
                bf16x8 v0 = *(const bf16x8*)(Vb + l31 * 128 + ((wd * 32 + b5 * 16) ^ sw31));
                o0 = __builtin_amdgcn_mfma_f32_32x32x16_bf16(v0, pB[wd], o0, 0, 0, 0);
                bf16x8 v1 = *(const bf16x8*)(Vb + (32 + l31) * 128 + ((wd * 32 + b5 * 16) ^ sw31));
                o1 = __builtin_amdgcn_mfma_f32_32x32x16_bf16(v1, pB[wd], o1, 0, 0, 0);
            }
            __builtin_amdgcn_s_setprio(0);
        }
        __builtin_amdgcn_s_barrier();
    }

    // epilogue: d = 32*half + 8g + 4b5 + j, q = wq + l31
    float inv = 1.f / lrun;
    size_t tok = (size_t)(b * SEQ + wq + l31);
    #pragma unroll
    for (int g = 0; g < 4; ++g) {
        us4 w0, w1;
        #pragma unroll
        for (int j = 0; j < 4; ++j) {
            w0[j] = f2bf(o0[g * 4 + j] * inv);
            w1[j] = f2bf(o1[g * 4 + j] * inv);
        }
        int d0 = g * 8 + b5 * 4;
        *(us4*)(&aout[tok * H + h * HD + d0]) = w0;
        *(us4*)(&aout[tok * H + h * HD + 32 + d0]) = w1;
    }
}

// ---------------------------------------------------------------------------
extern "C" void kernel_launch(void* const* d_in, const int* in_sizes, int n_in,
                              void* d_out, int out_size, void* d_ws, size_t ws_size,
                              hipStream_t stream) {
    const float* x      = (const float*)d_in[0];
    const float* W_qkv  = (const float*)d_in[1];
    const float* b_qkv  = (const float*)d_in[2];
    const float* W_proj = (const float*)d_in[3];
    const float* b_proj = (const float*)d_in[4];
    float* outp = (float*)d_out;

    char* ws = (char*)d_ws;
    unsigned short* xbf    = (unsigned short*)ws;  ws += (size_t)MTOK * H * 2;
    unsigned short* wqkvT  = (unsigned short*)ws;  ws += (size_t)N3H * H * 2;
    unsigned short* wprojT = (unsigned short*)ws;  ws += (size_t)H * H * 2;
    unsigned short* qkvb   = (unsigned short*)ws;  ws += (size_t)MTOK * N3H * 2;
    unsigned short* vtb    = (unsigned short*)ws;  ws += (size_t)BSZ * NH * 64 * SEQ * 2;
    unsigned short* aob    = (unsigned short*)ws;

    cvt_bf16<<<(MTOK * H) / (256 * 8), 256, 0, stream>>>(x, xbf, MTOK * H);
    tconv_bf16<<<dim3(N3H / 64, H / 64), 256, 0, stream>>>(W_qkv, wqkvT, H, N3H);
    tconv_bf16<<<dim3(H / 64, H / 64), 256, 0, stream>>>(W_proj, wprojT, H, H);

    // QKV: [16384,768] @ [768,2304] -> bf16   (grid 2304 % 8 == 0)
    gemm_bf16<<<(N3H / 128) * (MTOK / 128), 256, 0, stream>>>(
        xbf, wqkvT, b_qkv, qkvb, MTOK, N3H, H, 0);

    vtrans<<<dim3(SEQ / 64, NH, BSZ), 256, 0, stream>>>(qkvb, vtb);

    // attention: 1536 blocks, XCD-chunked, heavy-qb first
    attn_mfma<<<(SEQ / 128) * NH * BSZ, 256, 0, stream>>>(qkvb, vtb, aob);

    // proj: [16384,768] @ [768,768] -> fp32 out   (grid 768 % 8 == 0)
    gemm_bf16<<<(H / 128) * (MTOK / 128), 256, 0, stream>>>(
        aob, wprojT, b_proj, (void*)outp, MTOK, H, H, 1);
}

// Round 5
// 311.126 us; speedup vs baseline: 7.6916x; 1.0213x over previous
//
#include <hip/hip_runtime.h>

#define H 768
#define NH 12
#define HD 64
#define BSZ 16
#define SEQ 1024
#define MTOK (BSZ * SEQ)   // 16384
#define N3H (3 * H)        // 2304

typedef __attribute__((ext_vector_type(8))) short bf16x8;
typedef __attribute__((ext_vector_type(4))) float f32x4;
typedef __attribute__((ext_vector_type(16))) float f32x16;
typedef __attribute__((ext_vector_type(8))) unsigned short us8;
typedef __attribute__((ext_vector_type(4))) unsigned short us4;

__device__ __forceinline__ unsigned short f2bf(float f) {
    union { float f; unsigned u; } v; v.f = f;
    unsigned r = v.u + 0x7fffu + ((v.u >> 16) & 1u);   // RNE
    return (unsigned short)(r >> 16);
}

typedef __attribute__((address_space(1))) const unsigned int gu32_t;
typedef __attribute__((address_space(3))) unsigned int lu32_t;
__device__ __forceinline__ void glds16(const void* g, void* l) {
    __builtin_amdgcn_global_load_lds((gu32_t*)g, (lu32_t*)l, 16, 0, 0);
}

// ---------------------------------------------------------------------------
// fp32 -> bf16 elementwise convert (n multiple of 8)
// ---------------------------------------------------------------------------
__global__ __launch_bounds__(256) void cvt_bf16(
    const float* __restrict__ in, unsigned short* __restrict__ out, int n)
{
    int i = (blockIdx.x * 256 + threadIdx.x) * 8;
    if (i >= n) return;
    float4 a = *(const float4*)(in + i);
    float4 b = *(const float4*)(in + i + 4);
    us8 o;
    o[0]=f2bf(a.x); o[1]=f2bf(a.y); o[2]=f2bf(a.z); o[3]=f2bf(a.w);
    o[4]=f2bf(b.x); o[5]=f2bf(b.y); o[6]=f2bf(b.z); o[7]=f2bf(b.w);
    *(us8*)(out + i) = o;
}

// ---------------------------------------------------------------------------
// fp32 [Kd][Nd] -> bf16 transposed [Nd][Kd]  (64x64 LDS tiles)
// ---------------------------------------------------------------------------
__global__ __launch_bounds__(256) void tconv_bf16(
    const float* __restrict__ in, unsigned short* __restrict__ out, int Kd, int Nd)
{
    __shared__ float tile[64][65];
    int t = threadIdx.x;
    int n0 = blockIdx.x * 64, k0 = blockIdx.y * 64;
    #pragma unroll
    for (int r = 0; r < 4; ++r) {
        int kl = r * 16 + (t >> 4);
        float4 v = *(const float4*)(&in[(size_t)(k0 + kl) * Nd + n0 + (t & 15) * 4]);
        tile[kl][(t & 15) * 4 + 0] = v.x; tile[kl][(t & 15) * 4 + 1] = v.y;
        tile[kl][(t & 15) * 4 + 2] = v.z; tile[kl][(t & 15) * 4 + 3] = v.w;
    }
    __syncthreads();
    int nl = t >> 2, kc = (t & 3) * 16;
    us8 o0, o1;
    #pragma unroll
    for (int kk = 0; kk < 8; ++kk) o0[kk] = f2bf(tile[kc + kk][nl]);
    #pragma unroll
    for (int kk = 0; kk < 8; ++kk) o1[kk] = f2bf(tile[kc + 8 + kk][nl]);
    size_t ob = (size_t)(n0 + nl) * Kd + k0 + kc;
    *(us8*)(&out[ob]) = o0;
    *(us8*)(&out[ob + 8]) = o1;
}

// ---------------------------------------------------------------------------
// bf16 MFMA GEMM: C[M,N] = A[M,K] @ BT[N,K]^T + bias
// 128x128 tile, BK=64, 4 waves. Minimum-2-phase pipeline: LDS double-buffer,
// STAGE(t+1) issued BEFORE compute(t), counted vmcnt(8) so next tile's 8
// global_load_lds stay in flight across the whole compute phase.
// Cols < qscale_end are scaled by 0.125 in the epilogue (Q pre-scale).
// 1D grid with bijective XCD chunk swizzle (grid % 8 == 0 by caller).
// ---------------------------------------------------------------------------
__global__ __launch_bounds__(256) void gemm_bf16(
    const unsigned short* __restrict__ A, const unsigned short* __restrict__ BT,
    const float* __restrict__ bias, void* __restrict__ Cout,
    int M, int N, int K, int write_f32, int qscale_end)
{
    __shared__ char lds[65536];          // 2 x (A 16K | B 16K)
    const char* Ac = (const char*)A;
    const char* Bc = (const char*)BT;
    int t = threadIdx.x;
    int l = t & 63, w = t >> 6;
    int l16 = l & 15, l4 = l >> 4;
    int wm = w >> 1, wn = w & 1;

    int chunk = (int)gridDim.x >> 3;
    int lin = (blockIdx.x & 7) * chunk + (blockIdx.x >> 3);
    int nbx = N >> 7;
    int bx = lin % nbx, by = lin / nbx;
    int rowBase = by * 128, colBase = bx * 128;

    f32x4 acc[4][4];
    #pragma unroll
    for (int i = 0; i < 4; ++i)
        #pragma unroll
        for (int j = 0; j < 4; ++j) acc[i][j] = (f32x4){0, 0, 0, 0};

    auto STAGE = [&](int k0, int bi) {
        char* As = lds + bi * 32768;
        char* Bs = As + 16384;
        #pragma unroll
        for (int i = 0; i < 4; ++i) {
            int c = t + i * 256;             // 0..1023
            int row = c >> 3;
            int src = ((c & 7) * 16) ^ ((row & 7) << 4);
            glds16(Ac + ((size_t)(rowBase + row) * K + k0) * 2 + src, As + c * 16);
            glds16(Bc + ((size_t)(colBase + row) * K + k0) * 2 + src, Bs + c * 16);
        }
    };

    STAGE(0, 0);
    int nk = K >> 6;
    for (int kt = 0; kt < nk; ++kt) {
        int bi = kt & 1;
        if (kt + 1 < nk) {
            STAGE((kt + 1) << 6, bi ^ 1);    // next tile: stays in flight
            asm volatile("s_waitcnt vmcnt(8)" ::: "memory");
        } else {
            asm volatile("s_waitcnt vmcnt(0)" ::: "memory");
        }
        __builtin_amdgcn_s_barrier();

        const char* As = lds + bi * 32768;
        const char* Bs = As + 16384;
        #pragma unroll
        for (int kh = 0; kh < 2; ++kh) {
            bf16x8 af[4], bfr[4];
            #pragma unroll
            for (int mi = 0; mi < 4; ++mi) {
                int row = wm * 64 + mi * 16 + l16;
                af[mi] = *(const bf16x8*)(As + row * 128 + ((l4 * 16 + kh * 64) ^ ((row & 7) << 4)));
            }
            #pragma unroll
            for (int ni = 0; ni < 4; ++ni) {
                int row = wn * 64 + ni * 16 + l16;
                bfr[ni] = *(const bf16x8*)(Bs + row * 128 + ((l4 * 16 + kh * 64) ^ ((row & 7) << 4)));
            }
            #pragma unroll
            for (int mi = 0; mi < 4; ++mi)
                #pragma unroll
                for (int ni = 0; ni < 4; ++ni)
                    acc[mi][ni] = __builtin_amdgcn_mfma_f32_16x16x32_bf16(
                        af[mi], bfr[ni], acc[mi][ni], 0, 0, 0);
        }
        __builtin_amdgcn_s_barrier();
    }

    #pragma unroll
    for (int ni = 0; ni < 4; ++ni) {
        int col = colBase + wn * 64 + ni * 16 + l16;
        float bb = bias ? bias[col] : 0.f;
        float mul = (col < qscale_end) ? 0.125f : 1.0f;
        #pragma unroll
        for (int mi = 0; mi < 4; ++mi) {
            #pragma unroll
            for (int j = 0; j < 4; ++j) {
                int row = rowBase + wm * 64 + mi * 16 + l4 * 4 + j;
                float v = (acc[mi][ni][j] + bb) * mul;
                if (write_f32) ((float*)Cout)[(size_t)row * N + col] = v;
                else ((unsigned short*)Cout)[(size_t)row * N + col] = f2bf(v);
            }
        }
    }
}

// ---------------------------------------------------------------------------
// V transpose: qkv bf16 [MTOK][2304] (V part) -> vt bf16 [b][h][d=64][s=1024]
// ---------------------------------------------------------------------------
__global__ __launch_bounds__(256) void vtrans(
    const unsigned short* __restrict__ qkvb, unsigned short* __restrict__ vt)
{
    __shared__ char tile[64 * 128];
    int t = threadIdx.x;
    int st = blockIdx.x, h = blockIdx.y, b = blockIdx.z;
    int s0 = st * 64;
    {
        int s = t >> 2, dc = (t & 3) * 16;
        size_t g = (size_t)(b * SEQ + s0 + s) * N3H + 2 * H + h * HD + dc;
        us8 v0 = *(const us8*)(&qkvb[g]);
        us8 v1 = *(const us8*)(&qkvb[g + 8]);
        *(us8*)(tile + s * 128 + ((dc * 2) ^ ((s & 7) << 4))) = v0;
        *(us8*)(tile + s * 128 + ((dc * 2 + 16) ^ ((s & 7) << 4))) = v1;
    }
    __syncthreads();
    int d = t >> 2, sc = (t & 3) * 16;
    us8 o0, o1;
    #pragma unroll
    for (int kk = 0; kk < 8; ++kk) {
        int s = sc + kk;
        o0[kk] = *(const unsigned short*)(tile + s * 128 + ((d * 2) ^ ((s & 7) << 4)));
    }
    #pragma unroll
    for (int kk = 0; kk < 8; ++kk) {
        int s = sc + 8 + kk;
        o1[kk] = *(const unsigned short*)(tile + s * 128 + ((d * 2) ^ ((s & 7) << 4)));
    }
    size_t ob = ((size_t)((b * NH + h) * 64 + d)) * SEQ + s0 + sc;
    *(us8*)(&vt[ob]) = o0;
    *(us8*)(&vt[ob + 8]) = o1;
}

// ---------------------------------------------------------------------------
// Flash attention v4: 32x32x16 MFMA, 4 waves x 32 q. Q pre-scaled by 1/8 in
// the QKV GEMM epilogue (scores need no scaling here). T13 defer-rescale
// (THR=8). In-register P re-layout (1 shfl_xor(32)/window). K/V dbuf via
// global_load_lds(16) + counted vmcnt(4). XCD chunks, heavy-qb first.
// ---------------------------------------------------------------------------
__global__ __launch_bounds__(256, 4) void attn_mfma(
    const unsigned short* __restrict__ qkvb,
    const unsigned short* __restrict__ vt,
    unsigned short* __restrict__ aout)
{
    __shared__ char lds[32768];          // K dbuf 2x8K | V dbuf 2x8K
    char* Kbuf = lds;
    char* Vbuf = lds + 16384;
    int t = threadIdx.x;
    int l = t & 63, w = t >> 6;
    int l31 = l & 31, b5 = l >> 5;

    int lin = ((blockIdx.x & 7) * 192) + (blockIdx.x >> 3);   // XCD chunks
    int qb = 7 - (lin & 7);                                   // heavy first
    int bh = lin >> 3;
    int h = bh % NH, b = bh / NH;

    int wq = qb * 128 + w * 32;          // wave's 32 q rows
    int sw31 = (l31 & 7) << 4;
    int nt = 2 * qb + 2;
    int bhh = b * NH + h;
    const char* qkvc = (const char*)qkvb;
    const char* vtc  = (const char*)vt;

    // Q as B-fragments: col = q = l31, k = d = 16m + b5*8 + j  (pre-scaled)
    bf16x8 qB[4];
    {
        const unsigned short* qrow =
            qkvb + (size_t)(b * SEQ + wq + l31) * N3H + h * HD + b5 * 8;
        #pragma unroll
        for (int m = 0; m < 4; ++m) qB[m] = *(const bf16x8*)(qrow + m * 16);
    }

    auto STAGE = [&](int kt, int bi) {
        #pragma unroll
        for (int i = 0; i < 2; ++i) {
            int c = t + i * 256;
            int row = c >> 3;
            int src = ((c & 7) * 16) ^ ((row & 7) << 4);
            glds16(qkvc + ((size_t)(b * SEQ + kt * 64 + row) * N3H + H + h * HD) * 2 + src,
                   Kbuf + bi * 8192 + c * 16);
        }
        #pragma unroll
        for (int i = 0; i < 2; ++i) {
            int c = t + i * 256;
            int row = c >> 3;
            int src = ((c & 7) * 16) ^ ((row & 7) << 4);
            glds16(vtc + (((size_t)(bhh * 64 + row)) * SEQ + kt * 64) * 2 + src,
                   Vbuf + bi * 8192 + c * 16);
        }
    };

    STAGE(0, 0);
    __syncthreads();   // drains all vmem (Q regs + stage0); clean vmcnt state

    f32x16 o0, o1;
    #pragma unroll
    for (int r = 0; r < 16; ++r) { o0[r] = 0.f; o1[r] = 0.f; }
    float mrun = -1e30f, lrun = 0.f;

    for (int kt = 0; kt < nt; ++kt) {
        int bi = kt & 1;
        if (kt + 1 < nt) {
            STAGE(kt + 1, bi ^ 1);
            asm volatile("s_waitcnt vmcnt(4)" ::: "memory");
        } else {
            asm volatile("s_waitcnt vmcnt(0)" ::: "memory");
        }
        __builtin_amdgcn_s_barrier();

        int ktbase = kt * 64;
        if (ktbase <= wq + 31) {          // wave has unmasked work
            const char* Kb = Kbuf + bi * 8192;
            const char* Vb = Vbuf + bi * 8192;

            // S^T = K·Q^T : D rows = keys ((r&3)+8*(r>>2)+4*b5), cols = q
            f32x16 s[2];
            __builtin_amdgcn_s_setprio(1);
            #pragma unroll
            for (int st2 = 0; st2 < 2; ++st2) {
                f32x16 acc;
                #pragma unroll
                for (int r = 0; r < 16; ++r) acc[r] = 0.f;
                #pragma unroll
                for (int m = 0; m < 4; ++m) {
                    int row = st2 * 32 + l31;
                    bf16x8 kf = *(const bf16x8*)(Kb + row * 128 + ((m * 32 + b5 * 16) ^ sw31));
                    acc = __builtin_amdgcn_mfma_f32_32x32x16_bf16(kf, qB[m], acc, 0, 0, 0);
                }
                s[st2] = acc;
            }
            __builtin_amdgcn_s_setprio(0);

            if (ktbase + 63 > wq) {       // causal mask needed
                int q = wq + l31;
                #pragma unroll
                for (int st2 = 0; st2 < 2; ++st2)
                    #pragma unroll
                    for (int r = 0; r < 16; ++r) {
                        int key = ktbase + st2 * 32 + (r & 3) + 8 * (r >> 2) + 4 * b5;
                        if (key > q) s[st2][r] = -3e38f;
                    }
            }

            // online softmax: 31 in-lane fmax + 1 xor32; T13 defer-rescale
            float mx = s[0][0];
            #pragma unroll
            for (int r = 1; r < 16; ++r) mx = fmaxf(mx, s[0][r]);
            #pragma unroll
            for (int r = 0; r < 16; ++r) mx = fmaxf(mx, s[1][r]);
            mx = fmaxf(mx, __shfl_xor(mx, 32, 64));
            if (!__all(mx - mrun <= 8.f)) {
                float mnew = fmaxf(mrun, mx);
                float sc = __expf(mrun - mnew);
                mrun = mnew;
                lrun *= sc;
                #pragma unroll
                for (int r = 0; r < 16; ++r) { o0[r] *= sc; o1[r] *= sc; }
            }
            float rs = 0.f;
            #pragma unroll
            for (int st2 = 0; st2 < 2; ++st2)
                #pragma unroll
                for (int r = 0; r < 16; ++r) {
                    float p = __expf(s[st2][r] - mrun);
                    s[st2][r] = p;
                    rs += p;
                }
            rs += __shfl_xor(rs, 32, 64);
            lrun += rs;

            // P D-layout -> B-fragments, in-register (1 xor32 swap / window)
            bf16x8 pB[4];
            #pragma unroll
            for (int wd = 0; wd < 4; ++wd) {
                int st2 = wd >> 1, hf = (wd & 1) * 8;
                unsigned pk0 = (unsigned)f2bf(s[st2][hf + 0]) | ((unsigned)f2bf(s[st2][hf + 1]) << 16);
                unsigned pk1 = (unsigned)f2bf(s[st2][hf + 2]) | ((unsigned)f2bf(s[st2][hf + 3]) << 16);
                unsigned pk2 = (unsigned)f2bf(s[st2][hf + 4]) | ((unsigned)f2bf(s[st2][hf + 5]) << 16);
                unsigned pk3 = (unsigned)f2bf(s[st2][hf + 6]) | ((unsigned)f2bf(s[st2][hf + 7]) << 16);
                unsigned snd0 = b5 ? pk0 : pk2;
                unsigned snd1 = b5 ? pk1 : pk3;
                unsigned r0 = (unsigned)__shfl_xor((int)snd0, 32, 64);
                unsigned r1 = (unsigned)__shfl_xor((int)snd1, 32, 64);
                union { unsigned u[4]; bf16x8 v; } cvt;
                cvt.u[0] = b5 ? r0 : pk0;
                cvt.u[1] = b5 ? r1 : pk1;
                cvt.u[2] = b5 ? pk2 : r0;
                cvt.u[3] = b5 ? pk3 : r1;
                pB[wd] = cvt.v;
            }

            // O^T += V^T · P^T
            __builtin_amdgcn_s_setprio(1);
            #pragma unroll
            for (int wd = 0; wd < 4; ++wd) {
                bf16x8 v0 = *(const bf16x8*)(Vb + l31 * 128 + ((wd * 32 + b5 * 16) ^ sw31));
                o0 = __builtin_amdgcn_mfma_f32_32x32x16_bf16(v0, pB[wd], o0, 0, 0, 0);
                bf16x8 v1 = *(const bf16x8*)(Vb + (32 + l31) * 128 + ((wd * 32 + b5 * 16) ^ sw31));
                o1 = __builtin_amdgcn_mfma_f32_32x32x16_bf16(v1, pB[wd], o1, 0, 0, 0);
            }
            __builtin_amdgcn_s_setprio(0);
        }
        __builtin_amdgcn_s_barrier();
    }

    // epilogue: d = 32*half + 8g + 4b5 + j, q = wq + l31
    float inv = 1.f / lrun;
    size_t tok = (size_t)(b * SEQ + wq + l31);
    #pragma unroll
    for (int g = 0; g < 4; ++g) {
        us4 w0, w1;
        #pragma unroll
        for (int j = 0; j < 4; ++j) {
            w0[j] = f2bf(o0[g * 4 + j] * inv);
            w1[j] = f2bf(o1[g * 4 + j] * inv);
        }
        int d0 = g * 8 + b5 * 4;
        *(us4*)(&aout[tok * H + h * HD + d0]) = w0;
        *(us4*)(&aout[tok * H + h * HD + 32 + d0]) = w1;
    }
}

// ---------------------------------------------------------------------------
extern "C" void kernel_launch(void* const* d_in, const int* in_sizes, int n_in,
                              void* d_out, int out_size, void* d_ws, size_t ws_size,
                              hipStream_t stream) {
    const float* x      = (const float*)d_in[0];
    const float* W_qkv  = (const float*)d_in[1];
    const float* b_qkv  = (const float*)d_in[2];
    const float* W_proj = (const float*)d_in[3];
    const float* b_proj = (const float*)d_in[4];
    float* outp = (float*)d_out;

    char* ws = (char*)d_ws;
    unsigned short* xbf    = (unsigned short*)ws;  ws += (size_t)MTOK * H * 2;
    unsigned short* wqkvT  = (unsigned short*)ws;  ws += (size_t)N3H * H * 2;
    unsigned short* wprojT = (unsigned short*)ws;  ws += (size_t)H * H * 2;
    unsigned short* qkvb   = (unsigned short*)ws;  ws += (size_t)MTOK * N3H * 2;
    unsigned short* vtb    = (unsigned short*)ws;  ws += (size_t)BSZ * NH * 64 * SEQ * 2;
    unsigned short* aob    = (unsigned short*)ws;

    cvt_bf16<<<(MTOK * H) / (256 * 8), 256, 0, stream>>>(x, xbf, MTOK * H);
    tconv_bf16<<<dim3(N3H / 64, H / 64), 256, 0, stream>>>(W_qkv, wqkvT, H, N3H);
    tconv_bf16<<<dim3(H / 64, H / 64), 256, 0, stream>>>(W_proj, wprojT, H, H);

    // QKV: [16384,768] @ [768,2304] -> bf16, Q cols pre-scaled by 0.125
    gemm_bf16<<<(N3H / 128) * (MTOK / 128), 256, 0, stream>>>(
        xbf, wqkvT, b_qkv, qkvb, MTOK, N3H, H, 0, H);

    vtrans<<<dim3(SEQ / 64, NH, BSZ), 256, 0, stream>>>(qkvb, vtb);

    // attention: 1536 blocks, XCD-chunked, heavy-qb first
    attn_mfma<<<(SEQ / 128) * NH * BSZ, 256, 0, stream>>>(qkvb, vtb, aob);

    // proj: [16384,768] @ [768,768] -> fp32 out
    gemm_bf16<<<(H / 128) * (MTOK / 128), 256, 0, stream>>>(
        aob, wprojT, b_proj, (void*)outp, MTOK, H, H, 1, 0);
}